// Round 7
// baseline (195.238 us; speedup 1.0000x reference)
//
#include <hip/hip_runtime.h>
#include <stdint.h>

// INSTRUMENTATION ROUND (r7). Ledger: r1 66us, r2 64, r3(NT) 80, r4(vgpr-cap)
// 75, r5(full-unroll+reg-tables) 65, r6(16-row) 85 -- vs fill kernel 6.5 TB/s
// on the same buffer (our kernel: 2.44 TB/s). Issue-structure changes (r5) and
// LDS reorganizations (r2) were both neutral; counted pipe budgets predict
// ~25-30us. Our kernel's counters are invisible (rocprof top-5 = poison fills).
//
// Probe: pure-store kernel, EXACT same dispatch shape as the real kernel
// (2048 blocks x 256 thr, 19 guarded dwordx4/thread, 77.5KB/block region),
// writing constants to d_ws. Marginal dur_us delta = raw achievable store
// cost for this shape. Real kernel = r5 verbatim (writes d_out, absmax 0).
//   fork A: probe ~25-32us -> limiter internal to real kernel
//   fork B: probe ~55-70us -> limiter is the dispatch/store shape itself

#define D      16
#define NC     4845           // 1 + 16 + 136 + 816 + 3876 = C(20,4)
#define NPAD   4864           // 19*256 float4 chunks (padded, pad entries = 0)
#define POSPB  4              // rows per block; 4*4845 dwords = 4845 float4s
#define STRIDE 969            // LDS slots/pos: 1.0, x[16], o2[136], o3[816]
#define NIT    19             // store iterations per thread

typedef float    f4_t __attribute__((ext_vector_type(4)));
typedef uint32_t u4_t __attribute__((ext_vector_type(4)));

struct alignas(16) Tables {
    uint32_t chunk[NPAD * 4]; // per flat dword of a 4-row group (byte offs)
};

static constexpr Tables build_tables() {
    Tables t{};
    unsigned short A[NC] = {}, B[NC] = {};
    int pos = 0;
    A[pos] = 0; B[pos] = 0; ++pos;                        // ones: 1*1
    for (int i = 0; i < D; ++i) { A[pos] = 0; B[pos] = (unsigned short)(1 + i); ++pos; }
    long c[D] = {};
    for (int i = 0; i < D; ++i) c[i] = 1;
    int baseprev = 1;
    const int basecur[3] = {17, 153, 969};
    for (int it = 0; it < 3; ++it) {
        long S[D] = {};
        long acc = 0;
        for (int i = D - 1; i >= 0; --i) { acc += c[i]; S[i] = acc; }
        const long n = S[0];
        long off[D] = {};
        for (int i = 0; i < D; ++i) off[i] = n - S[i];
        for (long k = 0; k < n; ++k)                      // np.nonzero row-major
            for (int j = 0; j < D; ++j)
                if (k >= off[j]) {
                    A[pos] = (unsigned short)(baseprev + (int)k);
                    B[pos] = (unsigned short)(1 + j);
                    ++pos;
                }
        baseprev = basecur[it];
        for (int i = 0; i < D; ++i) c[i] = S[i];
    }
    for (int f = 0; f < NPAD * 4; ++f) {
        const int p = f / NC;
        const int ch = f - p * NC;
        if (p < POSPB)
            t.chunk[f] = (uint32_t)((p * STRIDE + A[ch]) * 4)
                       | ((uint32_t)((p * STRIDE + B[ch]) * 4) << 16);
        else
            t.chunk[f] = 0;
    }
    return t;
}

__device__ const Tables d_tables = build_tables();

// ---------------- probe: pure store, same shape, writes d_ws ----------------
__global__ __launch_bounds__(256) void probe_store(float* __restrict__ ws) {
    const int tid = threadIdx.x;
    const int blk = blockIdx.x;
    f4_t v;
    v.x = (float)tid; v.y = (float)blk; v.z = (float)(tid + 1); v.w = (float)(blk + 1);
    f4_t* __restrict__ o = (f4_t*)ws + (size_t)blk * NC;
    #pragma unroll 4
    for (int i = 0; i < NIT; ++i) {
        const int q = tid + i * 256;
        if (q < NC) o[q] = v;
    }
}

// ---------------- real kernel: r5 verbatim ----------------
__global__ __launch_bounds__(256) void moment_kernel(const float* __restrict__ in,
                                                     float* __restrict__ out) {
    __shared__ float lds[POSPB * STRIDE];   // 15504 B
    const int tid = threadIdx.x;
    const int blk = blockIdx.x;
    const uint32_t* __restrict__ dtab = d_tables.chunk;
    const u4_t* __restrict__ tab4 = (const u4_t*)dtab;

    u4_t e[NIT];
    #pragma unroll
    for (int i = 0; i < NIT; ++i) e[i] = tab4[tid + 256 * i];

    if (tid < 64) {
        const float v = in[(size_t)blk * (POSPB * D) + tid];
        lds[(tid >> 4) * STRIDE + 1 + (tid & 15)] = v;
    } else if (tid < 68) {
        lds[(tid - 64) * STRIDE] = 1.0f;
    }
    __syncthreads();

    for (int i = tid; i < 136 * POSPB; i += 256) {
        const int ch = 17 + (i >> 2);
        const int po = (i & 3) * STRIDE;
        const uint32_t t = dtab[ch];
        lds[po + ch] = lds[po + ((t & 0xFFFFu) >> 2)] * lds[po + (t >> 18)];
    }
    __syncthreads();

    for (int i = tid; i < 816 * POSPB; i += 256) {
        const int ch = 153 + (i >> 2);
        const int po = (i & 3) * STRIDE;
        const uint32_t t = dtab[ch];
        lds[po + ch] = lds[po + ((t & 0xFFFFu) >> 2)] * lds[po + (t >> 18)];
    }
    __syncthreads();

    f4_t* __restrict__ ochunk = (f4_t*)(out + (size_t)blk * (NC * POSPB));
    const char* __restrict__ lb = (const char*)lds;
    #pragma unroll
    for (int i = 0; i < NIT; ++i) {
        const int q = tid + i * 256;
        f4_t v;
        v.x = *(const float*)(lb + (e[i].x & 0xFFFFu)) * *(const float*)(lb + (e[i].x >> 16));
        v.y = *(const float*)(lb + (e[i].y & 0xFFFFu)) * *(const float*)(lb + (e[i].y >> 16));
        v.z = *(const float*)(lb + (e[i].z & 0xFFFFu)) * *(const float*)(lb + (e[i].z >> 16));
        v.w = *(const float*)(lb + (e[i].w & 0xFFFFu)) * *(const float*)(lb + (e[i].w >> 16));
        if (q < NC) ochunk[q] = v;
    }
}

extern "C" void kernel_launch(void* const* d_in, const int* in_sizes, int n_in,
                              void* d_out, int out_size, void* d_ws, size_t ws_size,
                              hipStream_t stream) {
    const float* in = (const float*)d_in[0];
    float* out = (float*)d_out;
    const int npos = in_sizes[0] / D;        // 8192
    const int nblk = npos / POSPB;           // 2048
    // Probe first (writes d_ws only), then the real kernel (writes d_out).
    // Stream order serializes them in the captured graph.
    if (ws_size >= (size_t)nblk * NC * sizeof(f4_t))
        probe_store<<<nblk, 256, 0, stream>>>((float*)d_ws);
    moment_kernel<<<nblk, 256, 0, stream>>>(in, out);
}